// Round 3
// baseline (2155.468 us; speedup 1.0000x reference)
//
#include <hip/hip_runtime.h>

// LSTM autoencoder: 4 layers (72->64), (64->32), (32->64), (64->72), B=512, T=512, fp32.
// Quad decomposition, TWO sequences per block (weights shared in regs across seqs),
// grid = 256 = one block per CU (no block serialization, no tail).
// x-chunks are prefetched per-lane straight into registers (no LDS round-trip);
// LDS holds only the double-buffered h vectors. One lgkmcnt-only barrier per step
// (out-stores and x-prefetch loads stay in flight across it).

#define B_ 512
#define T_ 512

__device__ __forceinline__ float fast_sigmoid(float x) {
    return __builtin_amdgcn_rcpf(1.0f + __expf(-x));
}
__device__ __forceinline__ float fast_tanh(float x) {
    // 1 - 2/(e^{2x}+1): saturates correctly to +/-1 for large |x|, no NaN.
    return 1.0f - 2.0f * __builtin_amdgcn_rcpf(__expf(2.0f * x) + 1.0f);
}

// Butterfly sum across a quad (lanes 4k..4k+3). quad_perm[1,0,3,2]=0xB1 (xor 1),
// quad_perm[2,3,0,1]=0x4E (xor 2). Result is bit-identical on all 4 lanes.
__device__ __forceinline__ float quad_allsum(float v) {
    int t = __builtin_amdgcn_update_dpp(0, __float_as_int(v), 0xB1, 0xF, 0xF, true);
    v += __int_as_float(t);
    t = __builtin_amdgcn_update_dpp(0, __float_as_int(v), 0x4E, 0xF, 0xF, true);
    v += __int_as_float(t);
    return v;
}

template <int IN, int H>
__global__ __launch_bounds__(4 * H, 1)   // minwaves=1: full 256 arch-VGPR budget; we run
                                         // exactly 1 block/CU (grid 256), so no co-residency
                                         // constraint — avoid the arch/AGPR split pathology.
void lstm_quad2(const float* __restrict__ x,    // [B, T, IN]
                const float* __restrict__ Wih,  // [4H, IN]
                const float* __restrict__ Whh,  // [4H, H]
                const float* __restrict__ bih,  // [4H]
                const float* __restrict__ bhh,  // [4H]
                float* __restrict__ out)        // [B, T, H]
{
    constexpr int IN4 = IN / 4;
    constexpr int H4  = H / 4;
    constexpr int KW4 = IN4 + H4;          // f4 chunks of [x_t | h]
    constexpr int CH  = (KW4 + 3) / 4;     // chunks per lane (last may be lane-guarded)
    constexpr int JX  = (IN4 + 3) / 4;     // x-chunks per lane
    static_assert(IN % 4 == 0 && H % 4 == 0, "vec4 layout");

    // Double-buffered h, per sequence. Step t reads hbuf[t&1], writes hbuf[(t+1)&1].
    __shared__ __align__(16) float4 hbuf[2][2][H4];

    const int tid = threadIdx.x;
    const int h   = tid >> 2;   // h-element owned by this quad
    const int q   = tid & 3;    // k-slice within the quad
    const size_t b0 = 2 * (size_t)blockIdx.x;
    const size_t b1 = b0 + 1;

    // ---- weight slices: 4 gate rows, chunks c = 4j+q (shared across both seqs) ----
    float4 w[4][CH] = {};
    float  bias[4];
#pragma unroll
    for (int gi = 0; gi < 4; ++gi) {
        const int r = h + gi * H;  // PyTorch gate order: i, f, g, o
        const float4* wi = reinterpret_cast<const float4*>(Wih + r * IN);
        const float4* wh = reinterpret_cast<const float4*>(Whh + r * H);
#pragma unroll
        for (int j = 0; j < CH; ++j) {
            const int ci = 4 * j + q;
            if (ci < KW4) w[gi][j] = (ci < IN4) ? wi[ci] : wh[ci - IN4];
        }
        bias[gi] = bih[r] + bhh[r];
    }

    const float4* xg0 = reinterpret_cast<const float4*>(x + b0 * T_ * IN);
    const float4* xg1 = reinterpret_cast<const float4*>(x + b1 * T_ * IN);
    float* outb0 = out + b0 * T_ * H;
    float* outb1 = out + b1 * T_ * H;

    // ---- init h = 0 ----
    if (tid < 2 * H4)
        hbuf[0][tid / H4][tid % H4] = make_float4(0.f, 0.f, 0.f, 0.f);

    // ---- per-lane x chunk registers, prefetched one step ahead ----
    float4 xr0[JX] = {}, xr1[JX] = {};
#pragma unroll
    for (int j = 0; j < JX; ++j) {
        const int ci = 4 * j + q;
        if (ci < IN4) { xr0[j] = xg0[ci]; xr1[j] = xg1[ci]; }  // x_0
    }
    float c0 = 0.f, c1 = 0.f;
    __syncthreads();

    for (int t = 0; t < T_; ++t) {
        const float4* __restrict__ hb0 = hbuf[t & 1][0];
        const float4* __restrict__ hb1 = hbuf[t & 1][1];

        // ---- dot: 2 seqs x 4 gates, x from regs, h from LDS broadcast ----
        float aA0[4] = {}, aB0[4] = {}, aA1[4] = {}, aB1[4] = {};
#pragma unroll
        for (int j = 0; j < CH; ++j) {
            const int ci = 4 * j + q;
            if (ci < KW4) {        // lane-guard only at the last chunk (e1/d2)
                float4 v0, v1;
                if (4 * j + 3 < IN4)      { v0 = xr0[j]; v1 = xr1[j]; }
                else if (4 * j >= IN4)    { v0 = hb0[ci - IN4]; v1 = hb1[ci - IN4]; }
                else {  // mixed chunk (only when IN4 % 4 != 0, i.e. e1)
                    if (ci < IN4) { v0 = xr0[j]; v1 = xr1[j]; }
                    else          { v0 = hb0[ci - IN4]; v1 = hb1[ci - IN4]; }
                }
#pragma unroll
                for (int gi = 0; gi < 4; ++gi) {
                    aA0[gi] = fmaf(w[gi][j].x, v0.x, fmaf(w[gi][j].y, v0.y, aA0[gi]));
                    aB0[gi] = fmaf(w[gi][j].z, v0.z, fmaf(w[gi][j].w, v0.w, aB0[gi]));
                    aA1[gi] = fmaf(w[gi][j].x, v1.x, fmaf(w[gi][j].y, v1.y, aA1[gi]));
                    aB1[gi] = fmaf(w[gi][j].z, v1.z, fmaf(w[gi][j].w, v1.w, aB1[gi]));
                }
            }
        }

        // ---- prefetch x_{t+1} into the just-consumed regs; flies across the barrier ----
        if (t + 1 < T_) {
#pragma unroll
            for (int j = 0; j < JX; ++j) {
                const int ci = 4 * j + q;
                if (ci < IN4) {
                    xr0[j] = xg0[(size_t)(t + 1) * IN4 + ci];
                    xr1[j] = xg1[(size_t)(t + 1) * IN4 + ci];
                }
            }
        }

        // ---- quad reduce + activations (bit-identical across the quad) ----
        const float i0 = fast_sigmoid(quad_allsum(aA0[0] + aB0[0]) + bias[0]);
        const float f0 = fast_sigmoid(quad_allsum(aA0[1] + aB0[1]) + bias[1]);
        const float g0 = fast_tanh   (quad_allsum(aA0[2] + aB0[2]) + bias[2]);
        const float o0 = fast_sigmoid(quad_allsum(aA0[3] + aB0[3]) + bias[3]);
        c0 = f0 * c0 + i0 * g0;
        const float hv0 = o0 * fast_tanh(c0);

        const float i1 = fast_sigmoid(quad_allsum(aA1[0] + aB1[0]) + bias[0]);
        const float f1 = fast_sigmoid(quad_allsum(aA1[1] + aB1[1]) + bias[1]);
        const float g1 = fast_tanh   (quad_allsum(aA1[2] + aB1[2]) + bias[2]);
        const float o1 = fast_sigmoid(quad_allsum(aA1[3] + aB1[3]) + bias[3]);
        c1 = f1 * c1 + i1 * g1;
        const float hv1 = o1 * fast_tanh(c1);

        // ---- publish h (lane q==0 -> seq0, q==1 -> seq1) + out store ----
        if (q == 0) {
            reinterpret_cast<float*>(hbuf[(t + 1) & 1][0])[h] = hv0;
            outb0[(size_t)t * H + h] = hv0;
        } else if (q == 1) {
            reinterpret_cast<float*>(hbuf[(t + 1) & 1][1])[h] = hv1;
            outb1[(size_t)t * H + h] = hv1;
        }

        // One barrier per step; drain LDS only. Global out-stores and x prefetch
        // loads retire asynchronously across steps (no vmcnt drain).
        asm volatile("s_waitcnt lgkmcnt(0)\n\ts_barrier" ::: "memory");
    }
}

extern "C" void kernel_launch(void* const* d_in, const int* in_sizes, int n_in,
                              void* d_out, int out_size, void* d_ws, size_t ws_size,
                              hipStream_t stream) {
    const float* x = (const float*)d_in[0];
    const float* e1_Wih = (const float*)d_in[1];
    const float* e1_Whh = (const float*)d_in[2];
    const float* e1_bih = (const float*)d_in[3];
    const float* e1_bhh = (const float*)d_in[4];
    const float* e2_Wih = (const float*)d_in[5];
    const float* e2_Whh = (const float*)d_in[6];
    const float* e2_bih = (const float*)d_in[7];
    const float* e2_bhh = (const float*)d_in[8];
    const float* d1_Wih = (const float*)d_in[9];
    const float* d1_Whh = (const float*)d_in[10];
    const float* d1_bih = (const float*)d_in[11];
    const float* d1_bhh = (const float*)d_in[12];
    const float* d2_Wih = (const float*)d_in[13];
    const float* d2_Whh = (const float*)d_in[14];
    const float* d2_bih = (const float*)d_in[15];
    const float* d2_bhh = (const float*)d_in[16];

    float* outp = (float*)d_out;

    // Scratch layout: ws0 = e2 out [512,512,32] (32 MB), ws1 = d1 out [512,512,64] (64 MB).
    // e1 out (64 MB) borrows d_out (75.5 MB) as scratch; d2 overwrites d_out with the
    // final [512,512,72] output (reads ws1, no overlap).
    float* ws0 = (float*)d_ws;
    float* ws1 = (float*)((char*)d_ws + (size_t)B_ * T_ * 32 * sizeof(float));

    const int GRID = B_ / 2;  // 256 blocks = 1 per CU, 2 sequences each

    // Layer e1: 72 -> 64  (256 threads = 64 quads)
    lstm_quad2<72, 64><<<GRID, 256, 0, stream>>>(
        x, e1_Wih, e1_Whh, e1_bih, e1_bhh, outp);
    // Layer e2: 64 -> 32  (128 threads = 32 quads)
    lstm_quad2<64, 32><<<GRID, 128, 0, stream>>>(
        outp, e2_Wih, e2_Whh, e2_bih, e2_bhh, ws0);
    // Layer d1: 32 -> 64
    lstm_quad2<32, 64><<<GRID, 256, 0, stream>>>(
        ws0, d1_Wih, d1_Whh, d1_bih, d1_bhh, ws1);
    // Layer d2: 64 -> 72  (288 threads = 72 quads)
    lstm_quad2<64, 72><<<GRID, 288, 0, stream>>>(
        ws1, d2_Wih, d2_Whh, d2_bih, d2_bhh, outp);
}

// Round 4
// 2105.044 us; speedup vs baseline: 1.0240x; 1.0240x over previous
//
#include <hip/hip_runtime.h>

// LSTM autoencoder: 4 layers (72->64), (64->32), (32->64), (64->72), B=512, T=512, fp32.
// OCTET decomposition: 8 lanes per h-element; lane q holds chunks c%8==q of all 4 gate
// rows (68 weight floats/lane) -> VGPR <= ~100 so TWO blocks co-reside per CU (grid 512,
// SEQ=1). The two blocks' barriers drift out of phase: one block's FMA issue fills the
// other's reduce/barrier/LDS-latency gaps. Gate allreduce = xor1,xor2 DPP + xor4
// ds_swizzle (bit-identical across the octet -> redundant c state coherent, no 2nd
// barrier). x_t staged through LDS by 16-18 lanes (one float4 prefetch reg), h
// double-buffered with x in one [x|h] buffer; one lgkmcnt-only barrier per step.

#define B_ 512
#define T_ 512

__device__ __forceinline__ float fast_sigmoid(float x) {
    return __builtin_amdgcn_rcpf(1.0f + __expf(-x));
}
__device__ __forceinline__ float fast_tanh(float x) {
    // 1 - 2/(e^{2x}+1): saturates correctly to +/-1 for large |x|, no NaN.
    return 1.0f - 2.0f * __builtin_amdgcn_rcpf(__expf(2.0f * x) + 1.0f);
}

// quad_perm[1,0,3,2]=0xB1 (xor 1), quad_perm[2,3,0,1]=0x4E (xor 2).
__device__ __forceinline__ float dpp_xor1_add(float v) {
    int t = __builtin_amdgcn_update_dpp(0, __float_as_int(v), 0xB1, 0xF, 0xF, true);
    return v + __int_as_float(t);
}
__device__ __forceinline__ float dpp_xor2_add(float v) {
    int t = __builtin_amdgcn_update_dpp(0, __float_as_int(v), 0x4E, 0xF, 0xF, true);
    return v + __int_as_float(t);
}
// ds_swizzle BitMode: offset = (xor<<10)|(or<<5)|and ; xor4 full-and: 0x101F.
__device__ __forceinline__ float swz_xor4_add(float v) {
    int t = __builtin_amdgcn_ds_swizzle(__float_as_int(v), 0x101F);
    return v + __int_as_float(t);
}
__device__ __forceinline__ float oct_allsum(float v) {
    return swz_xor4_add(dpp_xor2_add(dpp_xor1_add(v)));
}

template <int IN, int H, int MINW>
__global__ __launch_bounds__(8 * H, MINW)
void lstm_oct(const float* __restrict__ x,    // [B, T, IN]
              const float* __restrict__ Wih,  // [4H, IN]
              const float* __restrict__ Whh,  // [4H, H]
              const float* __restrict__ bih,  // [4H]
              const float* __restrict__ bhh,  // [4H]
              float* __restrict__ out)        // [B, T, H]
{
    constexpr int IN4 = IN / 4;
    constexpr int H4  = H / 4;
    constexpr int KW4 = IN4 + H4;          // float4 chunks of [x_t | h]
    constexpr int CH  = KW4 / 8;           // full chunks per lane
    constexpr int EX  = KW4 - 8 * CH;      // leftover chunks (0 or 2)
    static_assert(IN % 4 == 0 && H % 4 == 0, "vec4 layout");
    static_assert(EX == 0 || EX == 2, "leftover-chunk scheme expects 0 or 2");

    // Double-buffered [x | h]: step t reads kbuf[t&1], stages x_{t+1}/h_t into the other.
    __shared__ __align__(16) float4 kbuf[2][KW4];

    const int tid = threadIdx.x;
    const int h   = tid >> 3;   // h-element owned by this octet
    const int q   = tid & 7;    // k-slice within the octet
    const size_t b = blockIdx.x;

    // ---- weight slices: 4 gate rows, chunks c = 8j+q (68 floats/lane max) ----
    float4 w[4][CH];
    float4 we;                  // EX==2: extra chunk, gate q>>1, chunk 8*CH+(q&1)
    float  bias8[4];            // bias/8: allreduce over 8 lanes restores full bias
#pragma unroll
    for (int gi = 0; gi < 4; ++gi) {
        const int r = h + gi * H;  // PyTorch gate order: i, f, g, o
        const float4* wi = reinterpret_cast<const float4*>(Wih + (size_t)r * IN);
        const float4* wh = reinterpret_cast<const float4*>(Whh + (size_t)r * H);
#pragma unroll
        for (int j = 0; j < CH; ++j) {
            const int ci = 8 * j + q;
            w[gi][j] = (ci < IN4) ? wi[ci] : wh[ci - IN4];
        }
        bias8[gi] = 0.125f * (bih[r] + bhh[r]);
    }
    if constexpr (EX == 2) {
        const int ge = q >> 1;
        const int ce = 8 * CH + (q & 1);
        const int r  = h + ge * H;
        we = (ce < IN4)
           ? reinterpret_cast<const float4*>(Wih + (size_t)r * IN)[ce]
           : reinterpret_cast<const float4*>(Whh + (size_t)r * H)[ce - IN4];
    }

    const float4* xg   = reinterpret_cast<const float4*>(x + b * (size_t)T_ * IN);
    float*        outb = out + b * (size_t)T_ * H;

    // ---- init: x_0 into kbuf[0], h = 0; prefetch x_1 ----
    float4 xreg = make_float4(0.f, 0.f, 0.f, 0.f);
    if (tid < IN4) {
        kbuf[0][tid] = xg[tid];
        xreg = xg[IN4 + tid];          // x_1
    }
    if (tid < H4) kbuf[0][IN4 + tid] = make_float4(0.f, 0.f, 0.f, 0.f);
    float c = 0.0f;
    __syncthreads();

    for (int t = 0; t < T_; ++t) {
        const float4* kb  = kbuf[t & 1];
        float4*       kbn = kbuf[(t + 1) & 1];

        // stage x_{t+1} (nobody reads kbn this step); prefetch x_{t+2}
        if (t + 1 < T_ && tid < IN4) {
            kbn[tid] = xreg;
            if (t + 2 < T_) xreg = xg[(size_t)(t + 2) * IN4 + tid];
        }

        // ---- dot: each 16B LDS broadcast read feeds 16 FMAs (4 gates x 4 elems) ----
        float acc0 = bias8[0], acc1 = bias8[1], acc2 = bias8[2], acc3 = bias8[3];
#pragma unroll
        for (int j = 0; j < CH; ++j) {
            const float4 v = kb[8 * j + q];
            acc0 = fmaf(w[0][j].x, v.x, fmaf(w[0][j].y, v.y,
                   fmaf(w[0][j].z, v.z, fmaf(w[0][j].w, v.w, acc0))));
            acc1 = fmaf(w[1][j].x, v.x, fmaf(w[1][j].y, v.y,
                   fmaf(w[1][j].z, v.z, fmaf(w[1][j].w, v.w, acc1))));
            acc2 = fmaf(w[2][j].x, v.x, fmaf(w[2][j].y, v.y,
                   fmaf(w[2][j].z, v.z, fmaf(w[2][j].w, v.w, acc2))));
            acc3 = fmaf(w[3][j].x, v.x, fmaf(w[3][j].y, v.y,
                   fmaf(w[3][j].z, v.z, fmaf(w[3][j].w, v.w, acc3))));
        }
        if constexpr (EX == 2) {
            // leftover 2 chunks x 4 gates spread uniformly: lane q -> gate q>>1.
            const float4 v = kb[8 * CH + (q & 1)];
            const float  e = fmaf(we.x, v.x, fmaf(we.y, v.y,
                             fmaf(we.z, v.z, we.w * v.w)));
            const int ge = q >> 1;
            acc0 += (ge == 0) ? e : 0.0f;
            acc1 += (ge == 1) ? e : 0.0f;
            acc2 += (ge == 2) ? e : 0.0f;
            acc3 += (ge == 3) ? e : 0.0f;
        }

        // ---- octet allreduce + activations (bit-identical across the 8 lanes) ----
        const float iv = fast_sigmoid(oct_allsum(acc0));
        const float fv = fast_sigmoid(oct_allsum(acc1));
        const float gv = fast_tanh   (oct_allsum(acc2));
        const float ov = fast_sigmoid(oct_allsum(acc3));
        c = fv * c + iv * gv;
        const float hv = ov * fast_tanh(c);

        if (q == 0) {
            reinterpret_cast<float*>(kbn + IN4)[h] = hv;  // next step's h
            outb[(size_t)t * H + h] = hv;                 // 8 consecutive floats/wave
        }

        // One barrier per step; drain LDS only (h/x stage). Global out-stores and
        // x prefetch loads retire asynchronously across steps (no vmcnt drain).
        asm volatile("s_waitcnt lgkmcnt(0)\n\ts_barrier" ::: "memory");
    }
}

extern "C" void kernel_launch(void* const* d_in, const int* in_sizes, int n_in,
                              void* d_out, int out_size, void* d_ws, size_t ws_size,
                              hipStream_t stream) {
    const float* x = (const float*)d_in[0];
    const float* e1_Wih = (const float*)d_in[1];
    const float* e1_Whh = (const float*)d_in[2];
    const float* e1_bih = (const float*)d_in[3];
    const float* e1_bhh = (const float*)d_in[4];
    const float* e2_Wih = (const float*)d_in[5];
    const float* e2_Whh = (const float*)d_in[6];
    const float* e2_bih = (const float*)d_in[7];
    const float* e2_bhh = (const float*)d_in[8];
    const float* d1_Wih = (const float*)d_in[9];
    const float* d1_Whh = (const float*)d_in[10];
    const float* d1_bih = (const float*)d_in[11];
    const float* d1_bhh = (const float*)d_in[12];
    const float* d2_Wih = (const float*)d_in[13];
    const float* d2_Whh = (const float*)d_in[14];
    const float* d2_bih = (const float*)d_in[15];
    const float* d2_bhh = (const float*)d_in[16];

    float* outp = (float*)d_out;

    // Scratch layout: ws0 = e2 out [512,512,32] (32 MB), ws1 = d1 out [512,512,64] (64 MB).
    // e1 out (64 MB) borrows d_out (75.5 MB) as scratch; d2 overwrites d_out with the
    // final [512,512,72] output (reads ws1, no overlap).
    float* ws0 = (float*)d_ws;
    float* ws1 = (float*)((char*)d_ws + (size_t)B_ * T_ * 32 * sizeof(float));

    // grid 512 = 2 blocks/CU: two independent barrier groups drift out of phase.
    // Layer e1: 72 -> 64  (512 threads = 8 waves; 2 blocks = 16 waves @ <=128 VGPR)
    lstm_oct<72, 64, 4><<<B_, 512, 0, stream>>>(
        x, e1_Wih, e1_Whh, e1_bih, e1_bhh, outp);
    // Layer e2: 64 -> 32  (256 threads = 4 waves)
    lstm_oct<64, 32, 2><<<B_, 256, 0, stream>>>(
        outp, e2_Wih, e2_Whh, e2_bih, e2_bhh, ws0);
    // Layer d1: 32 -> 64  (512 threads)
    lstm_oct<32, 64, 4><<<B_, 512, 0, stream>>>(
        ws0, d1_Wih, d1_Whh, d1_bih, d1_bhh, ws1);
    // Layer d2: 64 -> 72  (576 threads = 9 waves; MINW=5 -> 102-VGPR cap so two
    // 9-wave blocks place as 5,5,4,4 waves/SIMD)
    lstm_oct<64, 72, 5><<<B_, 576, 0, stream>>>(
        ws1, d2_Wih, d2_Whh, d2_bih, d2_bhh, outp);
}

// Round 5
// 1455.334 us; speedup vs baseline: 1.4811x; 1.4464x over previous
//
#include <hip/hip_runtime.h>

// LSTM autoencoder, fused+pipelined: kernel A = {e1 72->64, e2 64->32}, kernel B =
// {d1 32->64, d2 64->72}. Within a block, layer L+1 runs one timestep behind layer L
// on its own wave-group: independent serial chains overlap, one barrier per super-step.
// h1/h3 never touch HBM (LDS only). 2 sequences per block (weights shared in regs),
// grid 256. Octet groups: 8 lanes/h, 2xDPP + ds_swizzle(xor4) allreduce (R4-verified).
// Quad group (d1): 4 lanes/h, 2xDPP allreduce (R1/R3-verified). Staging lanes live in
// the register-light group of each kernel to balance VGPR.

#define B_ 512
#define T_ 512

__device__ __forceinline__ float fast_sigmoid(float x) {
    return __builtin_amdgcn_rcpf(1.0f + __expf(-x));
}
__device__ __forceinline__ float fast_tanh(float x) {
    // 1 - 2/(e^{2x}+1): saturates to +/-1, no NaN.
    return 1.0f - 2.0f * __builtin_amdgcn_rcpf(__expf(2.0f * x) + 1.0f);
}
__device__ __forceinline__ float dpp_xor1_add(float v) {
    int t = __builtin_amdgcn_update_dpp(0, __float_as_int(v), 0xB1, 0xF, 0xF, true);
    return v + __int_as_float(t);
}
__device__ __forceinline__ float dpp_xor2_add(float v) {
    int t = __builtin_amdgcn_update_dpp(0, __float_as_int(v), 0x4E, 0xF, 0xF, true);
    return v + __int_as_float(t);
}
__device__ __forceinline__ float swz_xor4_add(float v) {
    int t = __builtin_amdgcn_ds_swizzle(__float_as_int(v), 0x101F);
    return v + __int_as_float(t);
}
__device__ __forceinline__ float oct_allsum(float v) {
    return swz_xor4_add(dpp_xor2_add(dpp_xor1_add(v)));
}
__device__ __forceinline__ float quad_allsum(float v) {
    return dpp_xor2_add(dpp_xor1_add(v));
}

// Octet dot over both sequences. kb* = [x|h] chunk arrays. EX==2: leftover 2 chunks
// spread as lane q -> gate q>>1, chunk 8*CH+(q&1) (R4-verified).
template <int IN4, int CH, int EX>
__device__ __forceinline__ void oct_dot2(const float4* kb0, const float4* kb1, int q,
                                         const float4 (&w)[4][CH], const float4 we,
                                         const float (&b8)[4],
                                         float (&a0)[4], float (&a1)[4]) {
#pragma unroll
    for (int gi = 0; gi < 4; ++gi) { a0[gi] = b8[gi]; a1[gi] = b8[gi]; }
#pragma unroll
    for (int j = 0; j < CH; ++j) {
        const float4 v0 = kb0[8 * j + q];
        const float4 v1 = kb1[8 * j + q];
#pragma unroll
        for (int gi = 0; gi < 4; ++gi) {
            a0[gi] = fmaf(w[gi][j].x, v0.x, fmaf(w[gi][j].y, v0.y,
                     fmaf(w[gi][j].z, v0.z, fmaf(w[gi][j].w, v0.w, a0[gi]))));
            a1[gi] = fmaf(w[gi][j].x, v1.x, fmaf(w[gi][j].y, v1.y,
                     fmaf(w[gi][j].z, v1.z, fmaf(w[gi][j].w, v1.w, a1[gi]))));
        }
    }
    if constexpr (EX == 2) {
        const float4 v0 = kb0[8 * CH + (q & 1)];
        const float4 v1 = kb1[8 * CH + (q & 1)];
        const float e0 = fmaf(we.x, v0.x, fmaf(we.y, v0.y, fmaf(we.z, v0.z, we.w * v0.w)));
        const float e1 = fmaf(we.x, v1.x, fmaf(we.y, v1.y, fmaf(we.z, v1.z, we.w * v1.w)));
        const int ge = q >> 1;
        a0[0] += (ge == 0) ? e0 : 0.f;  a1[0] += (ge == 0) ? e1 : 0.f;
        a0[1] += (ge == 1) ? e0 : 0.f;  a1[1] += (ge == 1) ? e1 : 0.f;
        a0[2] += (ge == 2) ? e0 : 0.f;  a1[2] += (ge == 2) ? e1 : 0.f;
        a0[3] += (ge == 3) ? e0 : 0.f;  a1[3] += (ge == 3) ? e1 : 0.f;
    }
}

__device__ __forceinline__ float lstm_fin_oct(const float (&a)[4], float& c) {
    const float i = fast_sigmoid(oct_allsum(a[0]));
    const float f = fast_sigmoid(oct_allsum(a[1]));
    const float g = fast_tanh   (oct_allsum(a[2]));
    const float o = fast_sigmoid(oct_allsum(a[3]));
    c = f * c + i * g;
    return o * fast_tanh(c);
}
__device__ __forceinline__ float lstm_fin_quad(const float (&a)[4], float& c) {
    const float i = fast_sigmoid(quad_allsum(a[0]));
    const float f = fast_sigmoid(quad_allsum(a[1]));
    const float g = fast_tanh   (quad_allsum(a[2]));
    const float o = fast_sigmoid(quad_allsum(a[3]));
    c = f * c + i * g;
    return o * fast_tanh(c);
}

#define STEP_BARRIER() asm volatile("s_waitcnt lgkmcnt(0)\n\ts_barrier" ::: "memory")

// ================= Kernel A: e1 (72->64, octet, lanes 0..511) + e2 (64->32, octet,
// lanes 512..767, also x-stagers). 2 seqs/block, grid 256. =================
__global__ __launch_bounds__(768, 3)
void lstm_fuse_A(const float* __restrict__ x,
                 const float* __restrict__ W1i, const float* __restrict__ W1h,
                 const float* __restrict__ b1i, const float* __restrict__ b1h,
                 const float* __restrict__ W2i, const float* __restrict__ W2h,
                 const float* __restrict__ b2i, const float* __restrict__ b2h,
                 float* __restrict__ out2)   // [B,T,32]
{
    // Abuf: e1 input [x(18)|h1(16)]; Bbuf: e2 input [h1(16)|h2(8)]. [buf][seq][chunk]
    __shared__ __align__(16) float4 Abuf[2][2][34];
    __shared__ __align__(16) float4 Bbuf[2][2][24];

    const int tid = threadIdx.x;
    const size_t b0 = 2 * (size_t)blockIdx.x, b1 = b0 + 1;

    if (tid < 512) {
        // -------- e1 group --------
        const int h = tid >> 3, q = tid & 7;
        float4 w[4][4]; float4 we; float b8[4];
#pragma unroll
        for (int gi = 0; gi < 4; ++gi) {
            const int r = h + gi * 64;
            const float4* wi = (const float4*)(W1i + (size_t)r * 72);
            const float4* wh = (const float4*)(W1h + (size_t)r * 64);
#pragma unroll
            for (int j = 0; j < 4; ++j) {
                const int ci = 8 * j + q;
                w[gi][j] = (ci < 18) ? wi[ci] : wh[ci - 18];
            }
            b8[gi] = 0.125f * (b1i[r] + b1h[r]);
        }
        {   // EX chunks 32,33 -> Whh chunks 14,15
            const int ge = q >> 1, r = h + ge * 64;
            we = ((const float4*)(W1h + (size_t)r * 64))[14 + (q & 1)];
        }
        // zero-init h1 (Abuf[0]) and h2 (Bbuf[0] and Bbuf[1])
        if (tid >= 256 && tid < 288) {
            const int l = tid - 256;               // 32: [s(2)][c(16)]
            Abuf[0][l >> 4][18 + (l & 15)] = make_float4(0.f, 0.f, 0.f, 0.f);
        }
        if (tid >= 288 && tid < 320) {
            const int l = tid - 288;               // 32: [buf(2)][s(2)][c(8)]
            Bbuf[(l >> 4) & 1][(l >> 3) & 1][16 + (l & 7)] = make_float4(0.f, 0.f, 0.f, 0.f);
        }
        float c0 = 0.f, c1 = 0.f;
        __syncthreads();

        for (int k = 0; k <= T_; ++k) {
            const int cur = k & 1, nxt = cur ^ 1;
            if (k < T_) {
                float a0[4], a1[4];
                oct_dot2<18, 4, 2>(Abuf[cur][0], Abuf[cur][1], q, w, we, b8, a0, a1);
                const float hv0 = lstm_fin_oct(a0, c0);
                const float hv1 = lstm_fin_oct(a1, c1);
                if (q == 0) {
                    ((float*)Abuf[nxt][0])[72 + h] = hv0;   // own next h1
                    ((float*)Bbuf[nxt][0])[h]      = hv0;   // e2 next input
                } else if (q == 1) {
                    ((float*)Abuf[nxt][1])[72 + h] = hv1;
                    ((float*)Bbuf[nxt][1])[h]      = hv1;
                }
            }
            STEP_BARRIER();
        }
    } else {
        // -------- e2 group (+ x stagers) --------
        const int l = tid - 512, h = l >> 3, q = l & 7;
        float4 w[4][3]; float b8[4];
#pragma unroll
        for (int gi = 0; gi < 4; ++gi) {
            const int r = h + gi * 32;
            const float4* wi = (const float4*)(W2i + (size_t)r * 64);
            const float4* wh = (const float4*)(W2h + (size_t)r * 32);
#pragma unroll
            for (int j = 0; j < 3; ++j) {
                const int ci = 8 * j + q;
                w[gi][j] = (ci < 16) ? wi[ci] : wh[ci - 16];
            }
            b8[gi] = 0.125f * (b2i[r] + b2h[r]);
        }
        // x stagers: l<18 -> seq0 chunk l; 64<=l<82 -> seq1 chunk l-64
        const bool st0 = (l < 18), st1 = (l >= 64 && l < 82);
        const int  sc  = st0 ? l : (l - 64);
        const float4* xg0 = (const float4*)(x + b0 * T_ * 72);
        const float4* xg1 = (const float4*)(x + b1 * T_ * 72);
        float4 xreg = make_float4(0.f, 0.f, 0.f, 0.f);
        if (st0) { Abuf[0][0][sc] = xg0[sc]; xreg = xg0[18 + sc]; }
        if (st1) { Abuf[0][1][sc] = xg1[sc]; xreg = xg1[18 + sc]; }
        float* o20 = out2 + b0 * (size_t)T_ * 32;
        float* o21 = out2 + b1 * (size_t)T_ * 32;
        float c0 = 0.f, c1 = 0.f;
        __syncthreads();

        for (int k = 0; k <= T_; ++k) {
            const int cur = k & 1, nxt = cur ^ 1;
            // stage x[k+1] into Abuf[nxt], prefetch x[k+2]
            if (k + 1 < T_) {
                if (st0) { Abuf[nxt][0][sc] = xreg;
                           if (k + 2 < T_) xreg = xg0[(size_t)(k + 2) * 18 + sc]; }
                if (st1) { Abuf[nxt][1][sc] = xreg;
                           if (k + 2 < T_) xreg = xg1[(size_t)(k + 2) * 18 + sc]; }
            }
            if (k >= 1) {
                float a0[4], a1[4];
                oct_dot2<16, 3, 0>(Bbuf[cur][0], Bbuf[cur][1], q, w,
                                   make_float4(0.f, 0.f, 0.f, 0.f), b8, a0, a1);
                const float hv0 = lstm_fin_oct(a0, c0);
                const float hv1 = lstm_fin_oct(a1, c1);
                if (q == 0) {
                    ((float*)Bbuf[nxt][0])[64 + h] = hv0;   // own next h2
                    o20[(size_t)(k - 1) * 32 + h]  = hv0;
                } else if (q == 1) {
                    ((float*)Bbuf[nxt][1])[64 + h] = hv1;
                    o21[(size_t)(k - 1) * 32 + h]  = hv1;
                }
            }
            STEP_BARRIER();
        }
    }
}

// ================= Kernel B: d1 (32->64, quad, lanes 0..255) + d2 (64->72, octet,
// lanes 256..831, also h2 stagers). 2 seqs/block, grid 256. =================
__global__ __launch_bounds__(832, 4)   // 13-wave block needs a 4-wave SIMD -> cap 128
void lstm_fuse_B(const float* __restrict__ h2in, // [B,T,32] (ws0)
                 const float* __restrict__ W3i, const float* __restrict__ W3h,
                 const float* __restrict__ b3i, const float* __restrict__ b3h,
                 const float* __restrict__ W4i, const float* __restrict__ W4h,
                 const float* __restrict__ b4i, const float* __restrict__ b4h,
                 float* __restrict__ out)       // [B,T,72]
{
    // Cbuf: d1 input [h2(8)|h3(16)]; Dbuf: d2 input [h3(16)|h4(18)].
    __shared__ __align__(16) float4 Cbuf[2][2][24];
    __shared__ __align__(16) float4 Dbuf[2][2][34];

    const int tid = threadIdx.x;
    const size_t b0 = 2 * (size_t)blockIdx.x, b1 = b0 + 1;

    if (tid < 256) {
        // -------- d1 group (quad: 4 lanes/h) --------
        const int h = tid >> 2, q = tid & 3;
        float4 w[4][6]; float b4[4];
#pragma unroll
        for (int gi = 0; gi < 4; ++gi) {
            const int r = h + gi * 64;
            const float4* wi = (const float4*)(W3i + (size_t)r * 32);
            const float4* wh = (const float4*)(W3h + (size_t)r * 64);
#pragma unroll
            for (int j = 0; j < 6; ++j) {
                const int ci = 4 * j + q;
                w[gi][j] = (ci < 8) ? wi[ci] : wh[ci - 8];
            }
            b4[gi] = 0.25f * (b3i[r] + b3h[r]);
        }
        // zero-init h3 (Cbuf[0]) and h4 (Dbuf[0], Dbuf[1])
        if (tid >= 128 && tid < 160) {
            const int l = tid - 128;               // 32: [s(2)][c(16)]
            Cbuf[0][l >> 4][8 + (l & 15)] = make_float4(0.f, 0.f, 0.f, 0.f);
        }
        if (tid < 72) {                            // 72: [buf(2)][s(2)][c(18)]
            const int buf = tid >= 36;
            const int r2  = tid - 36 * buf;
            const int s   = r2 >= 18;
            const int cc  = r2 - 18 * s;
            Dbuf[buf][s][16 + cc] = make_float4(0.f, 0.f, 0.f, 0.f);
        }
        float c0 = 0.f, c1 = 0.f;
        __syncthreads();

        for (int k = 0; k <= T_; ++k) {
            const int cur = k & 1, nxt = cur ^ 1;
            if (k < T_) {
                const float4* kb0 = Cbuf[cur][0];
                const float4* kb1 = Cbuf[cur][1];
                float a0[4], a1[4];
#pragma unroll
                for (int gi = 0; gi < 4; ++gi) { a0[gi] = b4[gi]; a1[gi] = b4[gi]; }
#pragma unroll
                for (int j = 0; j < 6; ++j) {
                    const float4 v0 = kb0[4 * j + q];
                    const float4 v1 = kb1[4 * j + q];
#pragma unroll
                    for (int gi = 0; gi < 4; ++gi) {
                        a0[gi] = fmaf(w[gi][j].x, v0.x, fmaf(w[gi][j].y, v0.y,
                                 fmaf(w[gi][j].z, v0.z, fmaf(w[gi][j].w, v0.w, a0[gi]))));
                        a1[gi] = fmaf(w[gi][j].x, v1.x, fmaf(w[gi][j].y, v1.y,
                                 fmaf(w[gi][j].z, v1.z, fmaf(w[gi][j].w, v1.w, a1[gi]))));
                    }
                }
                const float hv0 = lstm_fin_quad(a0, c0);
                const float hv1 = lstm_fin_quad(a1, c1);
                if (q == 0) {
                    ((float*)Cbuf[nxt][0])[32 + h] = hv0;   // own next h3
                    ((float*)Dbuf[nxt][0])[h]      = hv0;   // d2 next input
                } else if (q == 1) {
                    ((float*)Cbuf[nxt][1])[32 + h] = hv1;
                    ((float*)Dbuf[nxt][1])[h]      = hv1;
                }
            }
            STEP_BARRIER();
        }
    } else {
        // -------- d2 group (octet; also h2 stagers) --------
        const int l = tid - 256, h = l >> 3, q = l & 7;
        float4 w[4][4]; float4 we; float b8[4];
#pragma unroll
        for (int gi = 0; gi < 4; ++gi) {
            const int r = h + gi * 72;
            const float4* wi = (const float4*)(W4i + (size_t)r * 64);
            const float4* wh = (const float4*)(W4h + (size_t)r * 72);
#pragma unroll
            for (int j = 0; j < 4; ++j) {
                const int ci = 8 * j + q;
                w[gi][j] = (ci < 16) ? wi[ci] : wh[ci - 16];
            }
            b8[gi] = 0.125f * (b4i[r] + b4h[r]);
        }
        {   // EX chunks 32,33 -> Whh chunks 16,17
            const int ge = q >> 1, r = h + ge * 72;
            we = ((const float4*)(W4h + (size_t)r * 72))[16 + (q & 1)];
        }
        // h2 stagers: l<8 -> seq0 chunk l; 64<=l<72 -> seq1 chunk l-64
        const bool st0 = (l < 8), st1 = (l >= 64 && l < 72);
        const int  sc  = st0 ? l : (l - 64);
        const float4* g0 = (const float4*)(h2in + b0 * (size_t)T_ * 32);
        const float4* g1 = (const float4*)(h2in + b1 * (size_t)T_ * 32);
        float4 greg = make_float4(0.f, 0.f, 0.f, 0.f);
        if (st0) { Cbuf[0][0][sc] = g0[sc]; greg = g0[8 + sc]; }
        if (st1) { Cbuf[0][1][sc] = g1[sc]; greg = g1[8 + sc]; }
        float* ob0 = out + b0 * (size_t)T_ * 72;
        float* ob1 = out + b1 * (size_t)T_ * 72;
        float c0 = 0.f, c1 = 0.f;
        __syncthreads();

        for (int k = 0; k <= T_; ++k) {
            const int cur = k & 1, nxt = cur ^ 1;
            if (k + 1 < T_) {
                if (st0) { Cbuf[nxt][0][sc] = greg;
                           if (k + 2 < T_) greg = g0[(size_t)(k + 2) * 8 + sc]; }
                if (st1) { Cbuf[nxt][1][sc] = greg;
                           if (k + 2 < T_) greg = g1[(size_t)(k + 2) * 8 + sc]; }
            }
            if (k >= 1) {
                float a0[4], a1[4];
                oct_dot2<16, 4, 2>(Dbuf[cur][0], Dbuf[cur][1], q, w, we, b8, a0, a1);
                const float hv0 = lstm_fin_oct(a0, c0);
                const float hv1 = lstm_fin_oct(a1, c1);
                if (q == 0) {
                    ((float*)Dbuf[nxt][0])[64 + h] = hv0;   // own next h4
                    ob0[(size_t)(k - 1) * 72 + h]  = hv0;
                } else if (q == 1) {
                    ((float*)Dbuf[nxt][1])[64 + h] = hv1;
                    ob1[(size_t)(k - 1) * 72 + h]  = hv1;
                }
            }
            STEP_BARRIER();
        }
    }
}

extern "C" void kernel_launch(void* const* d_in, const int* in_sizes, int n_in,
                              void* d_out, int out_size, void* d_ws, size_t ws_size,
                              hipStream_t stream) {
    const float* x = (const float*)d_in[0];
    const float* e1_Wih = (const float*)d_in[1];
    const float* e1_Whh = (const float*)d_in[2];
    const float* e1_bih = (const float*)d_in[3];
    const float* e1_bhh = (const float*)d_in[4];
    const float* e2_Wih = (const float*)d_in[5];
    const float* e2_Whh = (const float*)d_in[6];
    const float* e2_bih = (const float*)d_in[7];
    const float* e2_bhh = (const float*)d_in[8];
    const float* d1_Wih = (const float*)d_in[9];
    const float* d1_Whh = (const float*)d_in[10];
    const float* d1_bih = (const float*)d_in[11];
    const float* d1_bhh = (const float*)d_in[12];
    const float* d2_Wih = (const float*)d_in[13];
    const float* d2_Whh = (const float*)d_in[14];
    const float* d2_bih = (const float*)d_in[15];
    const float* d2_bhh = (const float*)d_in[16];

    float* outp = (float*)d_out;
    float* ws0  = (float*)d_ws;   // e2 out [512,512,32] = 32 MB; h1/h3 stay in LDS

    // Kernel A: e1+e2 pipelined, 2 seqs/block.
    lstm_fuse_A<<<B_ / 2, 768, 0, stream>>>(
        x, e1_Wih, e1_Whh, e1_bih, e1_bhh,
        e2_Wih, e2_Whh, e2_bih, e2_bhh, ws0);
    // Kernel B: d1+d2 pipelined, 2 seqs/block.
    lstm_fuse_B<<<B_ / 2, 832, 0, stream>>>(
        ws0, d1_Wih, d1_Whh, d1_bih, d1_bhh,
        d2_Wih, d2_Whh, d2_bih, d2_bhh, outp);
}

// Round 6
// 1420.603 us; speedup vs baseline: 1.5173x; 1.0244x over previous
//
#include <hip/hip_runtime.h>

// LSTM autoencoder, fused+pipelined, overhead-minimized:
//   kernel A = e1(72->64, OCTET, 512 thr) + e2(64->32, QUAD, 128 thr) = 640 thr
//   kernel B = d1(32->64, QUAD, 256 thr) + d2(64->72, QUAD, 288 thr) = 544 thr
// 2 seqs/block, grid 256, layer L+1 one step behind L (R5-verified skew).
// New vs R5: (1) quad groups where VGPRs allow (fewer overhead-paying waves);
// (2) seq-split activations: lane computes only its sequence's act chain + single c
// (halves trans ops); (3) octet reduce is pure DPP: xor1, xor2, row_half_mirror
// (mirror == xor4 on quad-invariant partials) -- no ds_swizzle on the critical path.

#define B_ 512
#define T_ 512

__device__ __forceinline__ float fast_sigmoid(float x) {
    return __builtin_amdgcn_rcpf(1.0f + __expf(-x));
}
__device__ __forceinline__ float fast_tanh(float x) {
    return 1.0f - 2.0f * __builtin_amdgcn_rcpf(__expf(2.0f * x) + 1.0f);
}
__device__ __forceinline__ float dpp_xor1_add(float v) {
    int t = __builtin_amdgcn_update_dpp(0, __float_as_int(v), 0xB1, 0xF, 0xF, true);
    return v + __int_as_float(t);
}
__device__ __forceinline__ float dpp_xor2_add(float v) {
    int t = __builtin_amdgcn_update_dpp(0, __float_as_int(v), 0x4E, 0xF, 0xF, true);
    return v + __int_as_float(t);
}
// ROW_HALF_MIRROR (0x141): lane i <-> 7-i within each 8-lane half-row. After xor1+xor2
// allreduce the value is quad-invariant, so mirror (xor7) delivers the xor4 partner.
__device__ __forceinline__ float dpp_mirror8_add(float v) {
    int t = __builtin_amdgcn_update_dpp(0, __float_as_int(v), 0x141, 0xF, 0xF, true);
    return v + __int_as_float(t);
}
__device__ __forceinline__ float quad_allsum(float v) {
    return dpp_xor2_add(dpp_xor1_add(v));
}
__device__ __forceinline__ float oct_allsum(float v) {
    return dpp_mirror8_add(dpp_xor2_add(dpp_xor1_add(v)));
}

// -------- octet dot, 2 seqs (R5-verified). EX==2: lane q -> gate q>>1, chunk 8*CH+(q&1).
template <int IN4, int CH, int EX>
__device__ __forceinline__ void oct_dot2(const float4* kb0, const float4* kb1, int q,
                                         const float4 (&w)[4][CH], const float4 we,
                                         const float (&b8)[4],
                                         float (&a0)[4], float (&a1)[4]) {
#pragma unroll
    for (int gi = 0; gi < 4; ++gi) { a0[gi] = b8[gi]; a1[gi] = b8[gi]; }
#pragma unroll
    for (int j = 0; j < CH; ++j) {
        const float4 v0 = kb0[8 * j + q];
        const float4 v1 = kb1[8 * j + q];
#pragma unroll
        for (int gi = 0; gi < 4; ++gi) {
            a0[gi] = fmaf(w[gi][j].x, v0.x, fmaf(w[gi][j].y, v0.y,
                     fmaf(w[gi][j].z, v0.z, fmaf(w[gi][j].w, v0.w, a0[gi]))));
            a1[gi] = fmaf(w[gi][j].x, v1.x, fmaf(w[gi][j].y, v1.y,
                     fmaf(w[gi][j].z, v1.z, fmaf(w[gi][j].w, v1.w, a1[gi]))));
        }
    }
    if constexpr (EX == 2) {
        const float4 v0 = kb0[8 * CH + (q & 1)];
        const float4 v1 = kb1[8 * CH + (q & 1)];
        const float e0 = fmaf(we.x, v0.x, fmaf(we.y, v0.y, fmaf(we.z, v0.z, we.w * v0.w)));
        const float e1 = fmaf(we.x, v1.x, fmaf(we.y, v1.y, fmaf(we.z, v1.z, we.w * v1.w)));
        const int ge = q >> 1;
        a0[0] += (ge == 0) ? e0 : 0.f;  a1[0] += (ge == 0) ? e1 : 0.f;
        a0[1] += (ge == 1) ? e0 : 0.f;  a1[1] += (ge == 1) ? e1 : 0.f;
        a0[2] += (ge == 2) ? e0 : 0.f;  a1[2] += (ge == 2) ? e1 : 0.f;
        a0[3] += (ge == 3) ? e0 : 0.f;  a1[3] += (ge == 3) ? e1 : 0.f;
    }
}

// -------- quad dot, 2 seqs: chunks ci = 4j+q.
template <int CH>
__device__ __forceinline__ void quad_dot2(const float4* kb0, const float4* kb1, int q,
                                          const float4 (&w)[4][CH], const float (&b4)[4],
                                          float (&a0)[4], float (&a1)[4]) {
#pragma unroll
    for (int gi = 0; gi < 4; ++gi) { a0[gi] = b4[gi]; a1[gi] = b4[gi]; }
#pragma unroll
    for (int j = 0; j < CH; ++j) {
        const float4 v0 = kb0[4 * j + q];
        const float4 v1 = kb1[4 * j + q];
#pragma unroll
        for (int gi = 0; gi < 4; ++gi) {
            a0[gi] = fmaf(w[gi][j].x, v0.x, fmaf(w[gi][j].y, v0.y,
                     fmaf(w[gi][j].z, v0.z, fmaf(w[gi][j].w, v0.w, a0[gi]))));
            a1[gi] = fmaf(w[gi][j].x, v1.x, fmaf(w[gi][j].y, v1.y,
                     fmaf(w[gi][j].z, v1.z, fmaf(w[gi][j].w, v1.w, a1[gi]))));
        }
    }
}

// -------- seq-split finalize: allreduce all 8 sums, then ONE act chain for this lane's
// sequence (s = 0/1). Bit-identical within the lanes sharing (h, s).
__device__ __forceinline__ float lstm_fin_quad2(const float (&a0)[4], const float (&a1)[4],
                                                const int s, float& c) {
    float S[4];
#pragma unroll
    for (int g = 0; g < 4; ++g) {
        const float t0 = quad_allsum(a0[g]);
        const float t1 = quad_allsum(a1[g]);
        S[g] = s ? t1 : t0;
    }
    const float iv = fast_sigmoid(S[0]);
    const float fv = fast_sigmoid(S[1]);
    const float gv = fast_tanh(S[2]);
    const float ov = fast_sigmoid(S[3]);
    c = fv * c + iv * gv;
    return ov * fast_tanh(c);
}
__device__ __forceinline__ float lstm_fin_oct2(const float (&a0)[4], const float (&a1)[4],
                                               const int s, float& c) {
    float S[4];
#pragma unroll
    for (int g = 0; g < 4; ++g) {
        const float t0 = oct_allsum(a0[g]);
        const float t1 = oct_allsum(a1[g]);
        S[g] = s ? t1 : t0;
    }
    const float iv = fast_sigmoid(S[0]);
    const float fv = fast_sigmoid(S[1]);
    const float gv = fast_tanh(S[2]);
    const float ov = fast_sigmoid(S[3]);
    c = fv * c + iv * gv;
    return ov * fast_tanh(c);
}

#define STEP_BARRIER() asm volatile("s_waitcnt lgkmcnt(0)\n\ts_barrier" ::: "memory")

// ================= Kernel A: e1 octet (512) + e2 quad (128, + x stagers) =================
__global__ __launch_bounds__(640, 3)
void lstm_fuse_A(const float* __restrict__ x,
                 const float* __restrict__ W1i, const float* __restrict__ W1h,
                 const float* __restrict__ b1i, const float* __restrict__ b1h,
                 const float* __restrict__ W2i, const float* __restrict__ W2h,
                 const float* __restrict__ b2i, const float* __restrict__ b2h,
                 float* __restrict__ out2)   // [B,T,32]
{
    __shared__ __align__(16) float4 Abuf[2][2][34];  // e1 in: [x 18 | h1 16]
    __shared__ __align__(16) float4 Bbuf[2][2][24];  // e2 in: [h1 16 | h2 8]

    const int tid = threadIdx.x;
    const size_t b0 = 2 * (size_t)blockIdx.x, b1 = b0 + 1;

    if (tid < 512) {
        // -------- e1 octet --------
        const int h = tid >> 3, q = tid & 7, s = q >> 2;
        float4 w[4][4]; float4 we; float b8[4];
#pragma unroll
        for (int gi = 0; gi < 4; ++gi) {
            const int r = h + gi * 64;
            const float4* wi = (const float4*)(W1i + (size_t)r * 72);
            const float4* wh = (const float4*)(W1h + (size_t)r * 64);
#pragma unroll
            for (int j = 0; j < 4; ++j) {
                const int ci = 8 * j + q;
                w[gi][j] = (ci < 18) ? wi[ci] : wh[ci - 18];
            }
            b8[gi] = 0.125f * (b1i[r] + b1h[r]);
        }
        {   // EX chunks 32,33 -> Whh chunks 14,15
            const int ge = q >> 1, r = h + ge * 64;
            we = ((const float4*)(W1h + (size_t)r * 64))[14 + (q & 1)];
        }
        if (tid >= 256 && tid < 288) {
            const int l = tid - 256;
            Abuf[0][l >> 4][18 + (l & 15)] = make_float4(0.f, 0.f, 0.f, 0.f);
        }
        if (tid >= 288 && tid < 320) {
            const int l = tid - 288;
            Bbuf[(l >> 4) & 1][(l >> 3) & 1][16 + (l & 7)] = make_float4(0.f, 0.f, 0.f, 0.f);
        }
        float c = 0.f;
        __syncthreads();

        for (int k = 0; k <= T_; ++k) {
            const int cur = k & 1, nxt = cur ^ 1;
            if (k < T_) {
                float a0[4], a1[4];
                oct_dot2<18, 4, 2>(Abuf[cur][0], Abuf[cur][1], q, w, we, b8, a0, a1);
                const float hv = lstm_fin_oct2(a0, a1, s, c);
                if (q == 0) {
                    ((float*)Abuf[nxt][0])[72 + h] = hv;
                    ((float*)Bbuf[nxt][0])[h]      = hv;
                } else if (q == 4) {
                    ((float*)Abuf[nxt][1])[72 + h] = hv;
                    ((float*)Bbuf[nxt][1])[h]      = hv;
                }
            }
            STEP_BARRIER();
        }
    } else {
        // -------- e2 quad (+ x stagers) --------
        const int l = tid - 512, h = l >> 2, q = l & 3, s = q >> 1;
        float4 w[4][6]; float b4[4];
#pragma unroll
        for (int gi = 0; gi < 4; ++gi) {
            const int r = h + gi * 32;
            const float4* wi = (const float4*)(W2i + (size_t)r * 64);
            const float4* wh = (const float4*)(W2h + (size_t)r * 32);
#pragma unroll
            for (int j = 0; j < 6; ++j) {
                const int ci = 4 * j + q;
                w[gi][j] = (ci < 16) ? wi[ci] : wh[ci - 16];
            }
            b4[gi] = 0.25f * (b2i[r] + b2h[r]);
        }
        const bool st0 = (l < 18), st1 = (l >= 64 && l < 82);
        const int  sc  = st0 ? l : (l - 64);
        const float4* xg0 = (const float4*)(x + b0 * (size_t)T_ * 72);
        const float4* xg1 = (const float4*)(x + b1 * (size_t)T_ * 72);
        float4 xreg = make_float4(0.f, 0.f, 0.f, 0.f);
        if (st0) { Abuf[0][0][sc] = xg0[sc]; xreg = xg0[18 + sc]; }
        if (st1) { Abuf[0][1][sc] = xg1[sc]; xreg = xg1[18 + sc]; }
        float* o20 = out2 + b0 * (size_t)T_ * 32;
        float* o21 = out2 + b1 * (size_t)T_ * 32;
        float c = 0.f;
        __syncthreads();

        for (int k = 0; k <= T_; ++k) {
            const int cur = k & 1, nxt = cur ^ 1;
            if (k + 1 < T_) {
                if (st0) { Abuf[nxt][0][sc] = xreg;
                           if (k + 2 < T_) xreg = xg0[(size_t)(k + 2) * 18 + sc]; }
                if (st1) { Abuf[nxt][1][sc] = xreg;
                           if (k + 2 < T_) xreg = xg1[(size_t)(k + 2) * 18 + sc]; }
            }
            if (k >= 1) {
                float a0[4], a1[4];
                quad_dot2<6>(Bbuf[cur][0], Bbuf[cur][1], q, w, b4, a0, a1);
                const float hv = lstm_fin_quad2(a0, a1, s, c);
                if (q == 0) {
                    ((float*)Bbuf[nxt][0])[64 + h] = hv;
                    o20[(size_t)(k - 1) * 32 + h]  = hv;
                } else if (q == 2) {
                    ((float*)Bbuf[nxt][1])[64 + h] = hv;
                    o21[(size_t)(k - 1) * 32 + h]  = hv;
                }
            }
            STEP_BARRIER();
        }
    }
}

// ================= Kernel B: d1 quad (256, + h2 stagers) + d2 quad (288) =================
__global__ __launch_bounds__(544, 3)   // cap ~170 VGPR: 9-wave block must place 3,2,2,2
void lstm_fuse_B(const float* __restrict__ h2in, // [B,T,32]
                 const float* __restrict__ W3i, const float* __restrict__ W3h,
                 const float* __restrict__ b3i, const float* __restrict__ b3h,
                 const float* __restrict__ W4i, const float* __restrict__ W4h,
                 const float* __restrict__ b4i, const float* __restrict__ b4h,
                 float* __restrict__ out)       // [B,T,72]
{
    __shared__ __align__(16) float4 Cbuf[2][2][24];  // d1 in: [h2 8 | h3 16]
    __shared__ __align__(16) float4 Dbuf[2][2][34];  // d2 in: [h3 16 | h4 18]

    const int tid = threadIdx.x;
    const size_t b0 = 2 * (size_t)blockIdx.x, b1 = b0 + 1;

    if (tid < 256) {
        // -------- d1 quad (+ h2 stagers) --------
        const int h = tid >> 2, q = tid & 3, s = q >> 1;
        float4 w[4][6]; float b4[4];
#pragma unroll
        for (int gi = 0; gi < 4; ++gi) {
            const int r = h + gi * 64;
            const float4* wi = (const float4*)(W3i + (size_t)r * 32);
            const float4* wh = (const float4*)(W3h + (size_t)r * 64);
#pragma unroll
            for (int j = 0; j < 6; ++j) {
                const int ci = 4 * j + q;
                w[gi][j] = (ci < 8) ? wi[ci] : wh[ci - 8];
            }
            b4[gi] = 0.25f * (b3i[r] + b3h[r]);
        }
        if (tid >= 128 && tid < 160) {
            const int l = tid - 128;
            Cbuf[0][l >> 4][8 + (l & 15)] = make_float4(0.f, 0.f, 0.f, 0.f);
        }
        if (tid < 72) {
            const int buf = tid >= 36;
            const int r2  = tid - 36 * buf;
            const int sq  = r2 >= 18;
            const int cc  = r2 - 18 * sq;
            Dbuf[buf][sq][16 + cc] = make_float4(0.f, 0.f, 0.f, 0.f);
        }
        const bool st0 = (tid < 8), st1 = (tid >= 64 && tid < 72);
        const int  sc  = st0 ? tid : (tid - 64);
        const float4* g0 = (const float4*)(h2in + b0 * (size_t)T_ * 32);
        const float4* g1 = (const float4*)(h2in + b1 * (size_t)T_ * 32);
        float4 greg = make_float4(0.f, 0.f, 0.f, 0.f);
        if (st0) { Cbuf[0][0][sc] = g0[sc]; greg = g0[8 + sc]; }
        if (st1) { Cbuf[0][1][sc] = g1[sc]; greg = g1[8 + sc]; }
        float c = 0.f;
        __syncthreads();

        for (int k = 0; k <= T_; ++k) {
            const int cur = k & 1, nxt = cur ^ 1;
            if (k + 1 < T_) {
                if (st0) { Cbuf[nxt][0][sc] = greg;
                           if (k + 2 < T_) greg = g0[(size_t)(k + 2) * 8 + sc]; }
                if (st1) { Cbuf[nxt][1][sc] = greg;
                           if (k + 2 < T_) greg = g1[(size_t)(k + 2) * 8 + sc]; }
            }
            if (k < T_) {
                float a0[4], a1[4];
                quad_dot2<6>(Cbuf[cur][0], Cbuf[cur][1], q, w, b4, a0, a1);
                const float hv = lstm_fin_quad2(a0, a1, s, c);
                if (q == 0) {
                    ((float*)Cbuf[nxt][0])[32 + h] = hv;
                    ((float*)Dbuf[nxt][0])[h]      = hv;
                } else if (q == 2) {
                    ((float*)Cbuf[nxt][1])[32 + h] = hv;
                    ((float*)Dbuf[nxt][1])[h]      = hv;
                }
            }
            STEP_BARRIER();
        }
    } else {
        // -------- d2 quad --------
        const int l = tid - 256, h = l >> 2, q = l & 3, s = q >> 1;
        float4 w[4][8]; float4 we0_, we1_; float b4[4];
#pragma unroll
        for (int gi = 0; gi < 4; ++gi) {
            const int r = h + gi * 72;
            const float4* wi = (const float4*)(W4i + (size_t)r * 64);
            const float4* wh = (const float4*)(W4h + (size_t)r * 72);
#pragma unroll
            for (int j = 0; j < 8; ++j) {
                const int ci = 4 * j + q;
                w[gi][j] = (ci < 16) ? wi[ci] : wh[ci - 16];
            }
            b4[gi] = 0.25f * (b4i[r] + b4h[r]);
        }
        {   // EX: lane q -> gate q, chunks 32,33 -> Whh chunks 16,17
            const int r = h + q * 72;
            const float4* wh = (const float4*)(W4h + (size_t)r * 72);
            we0_ = wh[16]; we1_ = wh[17];
        }
        float* ob0 = out + b0 * (size_t)T_ * 72;
        float* ob1 = out + b1 * (size_t)T_ * 72;
        float c = 0.f;
        __syncthreads();

        for (int k = 0; k <= T_; ++k) {
            const int cur = k & 1, nxt = cur ^ 1;
            if (k >= 1) {
                float a0[4], a1[4];
                quad_dot2<8>(Dbuf[cur][0], Dbuf[cur][1], q, w, b4, a0, a1);
                {   // EX chunks (both seqs), gate q only
                    const float4 u0 = Dbuf[cur][0][32], u1 = Dbuf[cur][0][33];
                    const float4 u2 = Dbuf[cur][1][32], u3 = Dbuf[cur][1][33];
                    float e0 = fmaf(we0_.x, u0.x, fmaf(we0_.y, u0.y,
                               fmaf(we0_.z, u0.z, we0_.w * u0.w)));
                    e0 = fmaf(we1_.x, u1.x, fmaf(we1_.y, u1.y,
                         fmaf(we1_.z, u1.z, fmaf(we1_.w, u1.w, e0))));
                    float e1 = fmaf(we0_.x, u2.x, fmaf(we0_.y, u2.y,
                               fmaf(we0_.z, u2.z, we0_.w * u2.w)));
                    e1 = fmaf(we1_.x, u3.x, fmaf(we1_.y, u3.y,
                         fmaf(we1_.z, u3.z, fmaf(we1_.w, u3.w, e1))));
                    a0[0] += (q == 0) ? e0 : 0.f;  a1[0] += (q == 0) ? e1 : 0.f;
                    a0[1] += (q == 1) ? e0 : 0.f;  a1[1] += (q == 1) ? e1 : 0.f;
                    a0[2] += (q == 2) ? e0 : 0.f;  a1[2] += (q == 2) ? e1 : 0.f;
                    a0[3] += (q == 3) ? e0 : 0.f;  a1[3] += (q == 3) ? e1 : 0.f;
                }
                const float hv = lstm_fin_quad2(a0, a1, s, c);
                if (q == 0) {
                    ((float*)Dbuf[nxt][0])[64 + h] = hv;
                    ob0[(size_t)(k - 1) * 72 + h]  = hv;
                } else if (q == 2) {
                    ((float*)Dbuf[nxt][1])[64 + h] = hv;
                    ob1[(size_t)(k - 1) * 72 + h]  = hv;
                }
            }
            STEP_BARRIER();
        }
    }
}

extern "C" void kernel_launch(void* const* d_in, const int* in_sizes, int n_in,
                              void* d_out, int out_size, void* d_ws, size_t ws_size,
                              hipStream_t stream) {
    const float* x = (const float*)d_in[0];
    const float* e1_Wih = (const float*)d_in[1];
    const float* e1_Whh = (const float*)d_in[2];
    const float* e1_bih = (const float*)d_in[3];
    const float* e1_bhh = (const float*)d_in[4];
    const float* e2_Wih = (const float*)d_in[5];
    const float* e2_Whh = (const float*)d_in[6];
    const float* e2_bih = (const float*)d_in[7];
    const float* e2_bhh = (const float*)d_in[8];
    const float* d1_Wih = (const float*)d_in[9];
    const float* d1_Whh = (const float*)d_in[10];
    const float* d1_bih = (const float*)d_in[11];
    const float* d1_bhh = (const float*)d_in[12];
    const float* d2_Wih = (const float*)d_in[13];
    const float* d2_Whh = (const float*)d_in[14];
    const float* d2_bih = (const float*)d_in[15];
    const float* d2_bhh = (const float*)d_in[16];

    float* outp = (float*)d_out;
    float* ws0  = (float*)d_ws;   // e2 out [512,512,32] = 32 MB; h1/h3 stay in LDS

    lstm_fuse_A<<<B_ / 2, 640, 0, stream>>>(
        x, e1_Wih, e1_Whh, e1_bih, e1_bhh,
        e2_Wih, e2_Whh, e2_bih, e2_bhh, ws0);
    lstm_fuse_B<<<B_ / 2, 544, 0, stream>>>(
        ws0, d1_Wih, d1_Whh, d1_bih, d1_bhh,
        d2_Wih, d2_Whh, d2_bih, d2_bhh, outp);
}

// Round 7
// 1028.666 us; speedup vs baseline: 2.0954x; 1.3810x over previous
//
#include <hip/hip_runtime.h>

// LSTM autoencoder, ALL FOUR LAYERS in one kernel, f16-dot2 datapath.
//   groups: e1 quad (tid 0..255), e2 quad (256..383), d1 quad (384..639), d2 quad (640..927)
//   skew: layer L computes timestep k-L at super-step k; one barrier per super-step.
// Dots use v_dot2_f32_f16 (__builtin_amdgcn_fdot2): f16 pairs, fp32 accumulate ->
// 2 MACs/instr (halves dot issue), 16 k-elems per ds_read_b128 (halves LDS reads),
// and f16-packed weight regs (halves RF) which is what lets all 4 layers merge under
// the 1024-thread / 2048-VGPR pincer. c state and all reductions/activations stay fp32.
// h1/h2/h3 never touch HBM. Quad allreduce = xor1+xor2 DPP (R6-verified); seq-split
// activations (R6-verified).

#define B_ 512
#define T_ 512

typedef _Float16 h2 __attribute__((ext_vector_type(2)));
union U32H2 { unsigned int u; h2 h; };
__device__ __forceinline__ h2 bch2(unsigned int u) { U32H2 x; x.u = u; return x.h; }

__device__ __forceinline__ float fdot2(h2 a, h2 b, float c) {
#if __has_builtin(__builtin_amdgcn_fdot2)
    return __builtin_amdgcn_fdot2(a, b, c, false);
#else
    return c + (float)a.x * (float)b.x + (float)a.y * (float)b.y;
#endif
}

__device__ __forceinline__ float fast_sigmoid(float x) {
    return __builtin_amdgcn_rcpf(1.0f + __expf(-x));
}
__device__ __forceinline__ float fast_tanh(float x) {
    return 1.0f - 2.0f * __builtin_amdgcn_rcpf(__expf(2.0f * x) + 1.0f);
}
__device__ __forceinline__ float dpp_xor1_add(float v) {
    int t = __builtin_amdgcn_update_dpp(0, __float_as_int(v), 0xB1, 0xF, 0xF, true);
    return v + __int_as_float(t);
}
__device__ __forceinline__ float dpp_xor2_add(float v) {
    int t = __builtin_amdgcn_update_dpp(0, __float_as_int(v), 0x4E, 0xF, 0xF, true);
    return v + __int_as_float(t);
}
__device__ __forceinline__ float quad_allsum(float v) {
    return dpp_xor2_add(dpp_xor1_add(v));
}

// seq-split finalize (R6-verified): allreduce all 8 sums, one act chain for lane's seq.
__device__ __forceinline__ float lstm_fin_quad2(const float (&a0)[4], const float (&a1)[4],
                                                const int s, float& c) {
    float S[4];
#pragma unroll
    for (int g = 0; g < 4; ++g) {
        const float t0 = quad_allsum(a0[g]);
        const float t1 = quad_allsum(a1[g]);
        S[g] = s ? t1 : t0;
    }
    const float iv = fast_sigmoid(S[0]);
    const float fv = fast_sigmoid(S[1]);
    const float gv = fast_tanh(S[2]);
    const float ov = fast_sigmoid(S[3]);
    c = fv * c + iv * gv;
    return ov * fast_tanh(c);
}

// f16 quad dot, 2 seqs: lane q covers chunks ci = 4j+q (8 k-elems per chunk).
template <int CH>
__device__ __forceinline__ void qdot16(const uint4* __restrict__ r0,
                                       const uint4* __restrict__ r1, int q,
                                       const h2 (&w)[4][CH][4], const float (&b4)[4],
                                       float (&a0)[4], float (&a1)[4]) {
#pragma unroll
    for (int gi = 0; gi < 4; ++gi) { a0[gi] = b4[gi]; a1[gi] = b4[gi]; }
#pragma unroll
    for (int j = 0; j < CH; ++j) {
        const uint4 v0 = r0[4 * j + q];
        const uint4 v1 = r1[4 * j + q];
#pragma unroll
        for (int gi = 0; gi < 4; ++gi) {
            a0[gi] = fdot2(w[gi][j][3], bch2(v0.w), fdot2(w[gi][j][2], bch2(v0.z),
                     fdot2(w[gi][j][1], bch2(v0.y), fdot2(w[gi][j][0], bch2(v0.x), a0[gi]))));
            a1[gi] = fdot2(w[gi][j][3], bch2(v1.w), fdot2(w[gi][j][2], bch2(v1.z),
                     fdot2(w[gi][j][1], bch2(v1.y), fdot2(w[gi][j][0], bch2(v1.x), a1[gi]))));
        }
    }
}

// leftover chunk (17-chunk layers): lane q owns gate q's chunk 16.
__device__ __forceinline__ void ex_add16(const uint4 u0, const uint4 u1,
                                         const h2 (&wex)[4], int q,
                                         float (&a0)[4], float (&a1)[4]) {
    const float e0 = fdot2(wex[3], bch2(u0.w), fdot2(wex[2], bch2(u0.z),
                     fdot2(wex[1], bch2(u0.y), fdot2(wex[0], bch2(u0.x), 0.f))));
    const float e1 = fdot2(wex[3], bch2(u1.w), fdot2(wex[2], bch2(u1.z),
                     fdot2(wex[1], bch2(u1.y), fdot2(wex[0], bch2(u1.x), 0.f))));
    a0[0] += (q == 0) ? e0 : 0.f;  a1[0] += (q == 0) ? e1 : 0.f;
    a0[1] += (q == 1) ? e0 : 0.f;  a1[1] += (q == 1) ? e1 : 0.f;
    a0[2] += (q == 2) ? e0 : 0.f;  a1[2] += (q == 2) ? e1 : 0.f;
    a0[3] += (q == 3) ? e0 : 0.f;  a1[3] += (q == 3) ? e1 : 0.f;
}

// 8 fp32 -> 4 h2 (RN), one weight chunk.
__device__ __forceinline__ void ldw8(const float* __restrict__ src, h2 (&d)[4]) {
#pragma unroll
    for (int e = 0; e < 4; ++e) {
        h2 r = { (_Float16)src[2 * e], (_Float16)src[2 * e + 1] };
        d[e] = r;
    }
}
__device__ __forceinline__ uint2 pack4rn(float4 v) {
    h2 a = { (_Float16)v.x, (_Float16)v.y };
    h2 b = { (_Float16)v.z, (_Float16)v.w };
    U32H2 ua, ub; ua.h = a; ub.h = b;
    return make_uint2(ua.u, ub.u);
}

#define STEP_BARRIER() asm volatile("s_waitcnt lgkmcnt(0)\n\ts_barrier" ::: "memory")

__global__ __launch_bounds__(928, 4)   // cap 128 VGPR: 15 waves place 4,4,4,3 within RF
void lstm_mega(const float* __restrict__ x,
               const float* __restrict__ W1i, const float* __restrict__ W1h,
               const float* __restrict__ b1i, const float* __restrict__ b1h,
               const float* __restrict__ W2i, const float* __restrict__ W2h,
               const float* __restrict__ b2i, const float* __restrict__ b2h,
               const float* __restrict__ W3i, const float* __restrict__ W3h,
               const float* __restrict__ b3i, const float* __restrict__ b3h,
               const float* __restrict__ W4i, const float* __restrict__ W4h,
               const float* __restrict__ b4i, const float* __restrict__ b4h,
               float* __restrict__ out)   // [B,T,72]
{
    // f16 activation buffers, [parity][seq][k]. Rows 16B-aligned (lengths mult of 8).
    // A: e1 in [x 72 | h1 64] (136); B: e2 in [h1 64 | h2 32] (96);
    // C: d1 in [h2 32 | h3 64] (96);  D: d2 in [h3 64 | h4 72] (136).
    __shared__ __align__(16) _Float16 lds[2 * 2 * (136 + 96 + 96 + 136)];
    _Float16* Abuf = lds;               // 544
    _Float16* Bbuf = Abuf + 544;        // 384
    _Float16* Cbuf = Bbuf + 384;        // 384
    _Float16* Dbuf = Cbuf + 384;        // 544
#define AROW(p, s) (Abuf + ((p) * 2 + (s)) * 136)
#define BROW(p, s) (Bbuf + ((p) * 2 + (s)) * 96)
#define CROW(p, s) (Cbuf + ((p) * 2 + (s)) * 96)
#define DROW(p, s) (Dbuf + ((p) * 2 + (s)) * 136)

    const int tid = threadIdx.x;
    const size_t b0 = 2 * (size_t)blockIdx.x, b1 = b0 + 1;

    // zero everything once (h-regions need it; x-region overwritten below)
    for (int i = tid; i < 2 * 2 * (136 + 96 + 96 + 136); i += 928)
        lds[i] = (_Float16)0.f;
    __syncthreads();

    if (tid < 256) {
        // ================= e1: 72 -> 64, quad =================
        const int h = tid >> 2, q = tid & 3, s = q >> 1;
        h2 w[4][4][4]; h2 wex[4]; float b4v[4];
#pragma unroll
        for (int gi = 0; gi < 4; ++gi) {
            const int r = h + gi * 64;
#pragma unroll
            for (int j = 0; j < 4; ++j) {
                const int ci = 4 * j + q;
                const float* src = (ci < 9) ? (W1i + (size_t)r * 72 + 8 * ci)
                                            : (W1h + (size_t)r * 64 + 8 * ci - 72);
                ldw8(src, w[gi][j]);
            }
            b4v[gi] = 0.25f * (b1i[r] + b1h[r]);
        }
        ldw8(W1h + (size_t)(h + q * 64) * 64 + 56, wex);  // chunk 16 -> Whh k 56..63

        // x stagers: tid<18 seq0, 64<=tid<82 seq1 (chunk sc = 8 k-elems = 8B in f16)
        const bool st0 = (tid < 18), st1 = (tid >= 64 && tid < 82);
        const int  sc  = st0 ? tid : (tid - 64);
        const int  ss  = st0 ? 0 : 1;
        const float4* xg = (const float4*)(x + (st0 ? b0 : b1) * (size_t)T_ * 72);
        float4 xreg;
        if (st0 || st1) {
            float4 v = xg[sc];
            *(uint2*)((char*)AROW(0, ss) + sc * 8) = pack4rn(v);  // x[0]
            xreg = xg[18 + sc];                                   // x[1]
        }
        float c = 0.f;
        __syncthreads();

        for (int k = 0; k < T_ + 3; ++k) {
            const int cur = k & 1, nxt = cur ^ 1;
            if ((st0 || st1) && k + 1 < T_) {
                *(uint2*)((char*)AROW(nxt, ss) + sc * 8) = pack4rn(xreg);
                if (k + 2 < T_) xreg = xg[(size_t)(k + 2) * 18 + sc];
            }
            if (k < T_) {
                const uint4* r0 = (const uint4*)AROW(cur, 0);
                const uint4* r1 = (const uint4*)AROW(cur, 1);
                float a0[4], a1[4];
                qdot16<4>(r0, r1, q, w, b4v, a0, a1);
                ex_add16(r0[16], r1[16], wex, q, a0, a1);
                const float hv = lstm_fin_quad2(a0, a1, s, c);
                if (q == 0) { AROW(nxt, 0)[72 + h] = (_Float16)hv; BROW(nxt, 0)[h] = (_Float16)hv; }
                else if (q == 2) { AROW(nxt, 1)[72 + h] = (_Float16)hv; BROW(nxt, 1)[h] = (_Float16)hv; }
            }
            STEP_BARRIER();
        }
    } else if (tid < 384) {
        // ================= e2: 64 -> 32, quad =================
        const int l = tid - 256, h = l >> 2, q = l & 3, s = q >> 1;
        h2 w[4][3][4]; float b4v[4];
#pragma unroll
        for (int gi = 0; gi < 4; ++gi) {
            const int r = h + gi * 32;
#pragma unroll
            for (int j = 0; j < 3; ++j) {
                const int ci = 4 * j + q;
                const float* src = (ci < 8) ? (W2i + (size_t)r * 64 + 8 * ci)
                                            : (W2h + (size_t)r * 32 + 8 * ci - 64);
                ldw8(src, w[gi][j]);
            }
            b4v[gi] = 0.25f * (b2i[r] + b2h[r]);
        }
        float c = 0.f;
        __syncthreads();

        for (int k = 0; k < T_ + 3; ++k) {
            const int cur = k & 1, nxt = cur ^ 1;
            if (k >= 1 && k <= T_) {
                const uint4* r0 = (const uint4*)BROW(cur, 0);
                const uint4* r1 = (const uint4*)BROW(cur, 1);
                float a0[4], a1[4];
                qdot16<3>(r0, r1, q, w, b4v, a0, a1);
                const float hv = lstm_fin_quad2(a0, a1, s, c);
                if (q == 0) { BROW(nxt, 0)[64 + h] = (_Float16)hv; CROW(nxt, 0)[h] = (_Float16)hv; }
                else if (q == 2) { BROW(nxt, 1)[64 + h] = (_Float16)hv; CROW(nxt, 1)[h] = (_Float16)hv; }
            }
            STEP_BARRIER();
        }
    } else if (tid < 640) {
        // ================= d1: 32 -> 64, quad =================
        const int l = tid - 384, h = l >> 2, q = l & 3, s = q >> 1;
        h2 w[4][3][4]; float b4v[4];
#pragma unroll
        for (int gi = 0; gi < 4; ++gi) {
            const int r = h + gi * 64;
#pragma unroll
            for (int j = 0; j < 3; ++j) {
                const int ci = 4 * j + q;
                const float* src = (ci < 4) ? (W3i + (size_t)r * 32 + 8 * ci)
                                            : (W3h + (size_t)r * 64 + 8 * ci - 32);
                ldw8(src, w[gi][j]);
            }
            b4v[gi] = 0.25f * (b3i[r] + b3h[r]);
        }
        float c = 0.f;
        __syncthreads();

        for (int k = 0; k < T_ + 3; ++k) {
            const int cur = k & 1, nxt = cur ^ 1;
            if (k >= 2 && k <= T_ + 1) {
                const uint4* r0 = (const uint4*)CROW(cur, 0);
                const uint4* r1 = (const uint4*)CROW(cur, 1);
                float a0[4], a1[4];
                qdot16<3>(r0, r1, q, w, b4v, a0, a1);
                const float hv = lstm_fin_quad2(a0, a1, s, c);
                if (q == 0) { CROW(nxt, 0)[32 + h] = (_Float16)hv; DROW(nxt, 0)[h] = (_Float16)hv; }
                else if (q == 2) { CROW(nxt, 1)[32 + h] = (_Float16)hv; DROW(nxt, 1)[h] = (_Float16)hv; }
            }
            STEP_BARRIER();
        }
    } else {
        // ================= d2: 64 -> 72, quad =================
        const int l = tid - 640, h = l >> 2, q = l & 3, s = q >> 1;
        h2 w[4][4][4]; h2 wex[4]; float b4v[4];
#pragma unroll
        for (int gi = 0; gi < 4; ++gi) {
            const int r = h + gi * 72;
#pragma unroll
            for (int j = 0; j < 4; ++j) {
                const int ci = 4 * j + q;
                const float* src = (ci < 8) ? (W4i + (size_t)r * 64 + 8 * ci)
                                            : (W4h + (size_t)r * 72 + 8 * ci - 64);
                ldw8(src, w[gi][j]);
            }
            b4v[gi] = 0.25f * (b4i[r] + b4h[r]);
        }
        ldw8(W4h + (size_t)(h + q * 72) * 72 + 64, wex);  // chunk 16 -> Whh k 64..71
        float* ob0 = out + b0 * (size_t)T_ * 72;
        float* ob1 = out + b1 * (size_t)T_ * 72;
        float c = 0.f;
        __syncthreads();

        for (int k = 0; k < T_ + 3; ++k) {
            const int cur = k & 1, nxt = cur ^ 1;
            if (k >= 3) {
                const int t = k - 3;
                const uint4* r0 = (const uint4*)DROW(cur, 0);
                const uint4* r1 = (const uint4*)DROW(cur, 1);
                float a0[4], a1[4];
                qdot16<4>(r0, r1, q, w, b4v, a0, a1);
                ex_add16(r0[16], r1[16], wex, q, a0, a1);
                const float hv = lstm_fin_quad2(a0, a1, s, c);
                if (q == 0) { DROW(nxt, 0)[64 + h] = (_Float16)hv; ob0[(size_t)t * 72 + h] = hv; }
                else if (q == 2) { DROW(nxt, 1)[64 + h] = (_Float16)hv; ob1[(size_t)t * 72 + h] = hv; }
            }
            STEP_BARRIER();
        }
    }
#undef AROW
#undef BROW
#undef CROW
#undef DROW
}

extern "C" void kernel_launch(void* const* d_in, const int* in_sizes, int n_in,
                              void* d_out, int out_size, void* d_ws, size_t ws_size,
                              hipStream_t stream) {
    const float* x = (const float*)d_in[0];
    const float* e1_Wih = (const float*)d_in[1];
    const float* e1_Whh = (const float*)d_in[2];
    const float* e1_bih = (const float*)d_in[3];
    const float* e1_bhh = (const float*)d_in[4];
    const float* e2_Wih = (const float*)d_in[5];
    const float* e2_Whh = (const float*)d_in[6];
    const float* e2_bih = (const float*)d_in[7];
    const float* e2_bhh = (const float*)d_in[8];
    const float* d1_Wih = (const float*)d_in[9];
    const float* d1_Whh = (const float*)d_in[10];
    const float* d1_bih = (const float*)d_in[11];
    const float* d1_bhh = (const float*)d_in[12];
    const float* d2_Wih = (const float*)d_in[13];
    const float* d2_Whh = (const float*)d_in[14];
    const float* d2_bih = (const float*)d_in[15];
    const float* d2_bhh = (const float*)d_in[16];

    lstm_mega<<<B_ / 2, 928, 0, stream>>>(
        x,
        e1_Wih, e1_Whh, e1_bih, e1_bhh,
        e2_Wih, e2_Whh, e2_bih, e2_bhh,
        d1_Wih, d1_Whh, d1_bih, d1_bhh,
        d2_Wih, d2_Whh, d2_bih, d2_bhh,
        (float*)d_out);
}